// Round 3
// baseline (406.842 us; speedup 1.0000x reference)
//
#include <hip/hip_runtime.h>

#define Bz 64
#define Nn 577
#define Cc 768
#define Hh 12
#define Dd 64
#define SCALE 0.125f

typedef __attribute__((ext_vector_type(8))) short short8;
typedef __attribute__((ext_vector_type(4))) float float4v;

__device__ __forceinline__ unsigned short bf16rne(float f) {
  unsigned u = __float_as_uint(f);
  u += 0x7FFFu + ((u >> 16) & 1u);
  return (unsigned short)(u >> 16);
}

// ws layout (float units), total 1,918,464 floats = 7.67 MB:
//   rb     @ 0        : 786,432 bf16 (= 393,216 float slots)  [B][24 s][4 q][16 m][8 j]
//   logits @ 393216   : [B][H][N]  fp32
//   attnT  @ 836352   : [B][N][H]  fp32
//   y      @ 1279488  : [B][H][C]  fp32 (zeroed, atomic-accumulated)
//   cls    @ 1869312  : [B][C]

// ================= k_qr: q then r -> rb (bf16, MFMA-A layout) =================
// grid 12 h x 8 b-groups = 96 blocks, block 256. W traffic: 2x196 KB/block.
__global__ __launch_bounds__(256) void k_qr(const float* __restrict__ x,
                                            const float* __restrict__ qkv_w,
                                            const float* __restrict__ qkv_b,
                                            unsigned short* __restrict__ rb) {
  int h = blockIdx.x % Hh, bg = blockIdx.x / Hh;
  int t = threadIdx.x;
  __shared__ float xs[8][Cc];          // 24.6 KB
  __shared__ float qpart[64][4][8];    // 8 KB
  __shared__ float qs2[64][8];         // 2 KB  [d][bb]
  // stage x[bg*8+bb][0][:]
  for (int idx = t; idx < 8 * (Cc / 4); idx += 256) {
    int bb = idx / 192, c4 = idx % 192;
    ((float4*)&xs[bb][0])[c4] =
        ((const float4*)(x + (size_t)(bg * 8 + bb) * Nn * Cc))[c4];
  }
  __syncthreads();
  // phase 1: q partials. thread (d = t>>2, sub = t&3) covers c-quarter.
  {
    int d = t >> 2, sub = t & 3;
    float acc[8];
#pragma unroll
    for (int bb = 0; bb < 8; ++bb) acc[bb] = 0.f;
    const float4* wq = (const float4*)(qkv_w + (size_t)(h * Dd + d) * Cc + sub * 192);
#pragma unroll 4
    for (int c4 = 0; c4 < 48; ++c4) {
      float4 w = wq[c4];
#pragma unroll
      for (int bb = 0; bb < 8; ++bb) {
        float4 xv = ((const float4*)&xs[bb][sub * 192])[c4];
        acc[bb] += w.x * xv.x + w.y * xv.y + w.z * xv.z + w.w * xv.w;
      }
    }
#pragma unroll
    for (int bb = 0; bb < 8; ++bb) qpart[d][sub][bb] = acc[bb];
  }
  __syncthreads();
  for (int idx = t; idx < 512; idx += 256) {
    int bb = idx >> 6, d = idx & 63;
    qs2[d][bb] = qpart[d][0][bb] + qpart[d][1][bb] + qpart[d][2][bb] +
                 qpart[d][3][bb] + qkv_b[h * Dd + d];
  }
  __syncthreads();
  // phase 2: r[bb][c] = SCALE * sum_d q[bb][d] * Wk[h*64+d][c], 3 c's per thread
  {
    float acc[8][3];
#pragma unroll
    for (int bb = 0; bb < 8; ++bb)
#pragma unroll
      for (int i = 0; i < 3; ++i) acc[bb][i] = 0.f;
    const float* wk = qkv_w + (size_t)(Cc + h * Dd) * Cc;
    for (int d = 0; d < Dd; ++d) {
      float w0 = wk[(size_t)d * Cc + t];
      float w1 = wk[(size_t)d * Cc + t + 256];
      float w2 = wk[(size_t)d * Cc + t + 512];
      float4 qa = *(const float4*)&qs2[d][0];
      float4 qb = *(const float4*)&qs2[d][4];
      float qv[8] = {qa.x, qa.y, qa.z, qa.w, qb.x, qb.y, qb.z, qb.w};
#pragma unroll
      for (int bb = 0; bb < 8; ++bb) {
        acc[bb][0] += qv[bb] * w0;
        acc[bb][1] += qv[bb] * w1;
        acc[bb][2] += qv[bb] * w2;
      }
    }
#pragma unroll
    for (int bb = 0; bb < 8; ++bb) {
      size_t base = (size_t)(bg * 8 + bb) * 12288 + h * 8;
#pragma unroll
      for (int i = 0; i < 3; ++i) {
        int c = t + i * 256;
        int s = c >> 5, qq = (c >> 3) & 3, j = c & 7;
        rb[base + s * 512 + qq * 128 + j] = bf16rne(acc[bb][i] * SCALE);
      }
    }
  }
}

// ====== k_main: copy x->out[:,1:], convert tile to bf16 LDS, MFMA logits ======
// grid 64 b x 19 tiles (32 rows), block 256 (4 waves; waves 0,1 do MFMA).
#define MT 32
#define MNT 19
#define XLD 776   // bf16 row stride: 768+8 pad -> 2-way banks max
__global__ __launch_bounds__(256) void k_main(const float* __restrict__ x,
                                              const unsigned short* __restrict__ rb,
                                              float* __restrict__ out,
                                              float* __restrict__ logits) {
  int b = blockIdx.x / MNT, tile = blockIdx.x % MNT;
  int n0 = tile * MT;
  int t = threadIdx.x;
  __shared__ unsigned short ab[12288];      // 24.5 KB: A fragments
  __shared__ unsigned short xb[MT * XLD];   // 49.7 KB: B tile bf16
  // phase 0: rb -> LDS (1536 uint4)
  {
    const uint4* rbu = (const uint4*)(rb + (size_t)b * 12288);
    uint4* abu = (uint4*)ab;
#pragma unroll
    for (int i = 0; i < 6; ++i) abu[i * 256 + t] = rbu[i * 256 + t];
  }
  // phase 1: stream 32 rows: load fp32 -> store out -> cvt bf16 -> LDS
  {
    const float4* xg = (const float4*)(x + (size_t)b * Nn * Cc);
    float4* og = (float4*)(out + (size_t)b * Nn * Cc);
#pragma unroll 6
    for (int i = 0; i < 24; ++i) {
      int lin = i * 256 + t;
      int row = lin / 192, c4 = lin % 192;
      int n = n0 + row;
      float4 v = make_float4(0.f, 0.f, 0.f, 0.f);
      if (n < Nn) v = xg[(size_t)n * 192 + c4];
      if (n >= 1 && n < Nn) og[(size_t)n * 192 + c4] = v;
      ushort4 hv;
      hv.x = bf16rne(v.x); hv.y = bf16rne(v.y);
      hv.z = bf16rne(v.z); hv.w = bf16rne(v.w);
      *(ushort4*)&xb[row * XLD + c4 * 4] = hv;
    }
  }
  __syncthreads();
  // phase 2: waves 0,1: 16-row subtile each, 24 MFMA over K=768
  int wave = t >> 6, lane = t & 63;
  if (wave < 2) {
    int m = lane & 15, q = lane >> 4;
    int lr = wave * 16 + m;  // local row = B's n-col
    float4v acc = {0.f, 0.f, 0.f, 0.f};
#pragma unroll
    for (int s = 0; s < 24; ++s) {
      short8 a = *(const short8*)&ab[s * 512 + q * 128 + m * 8];
      short8 bf = *(const short8*)&xb[lr * XLD + s * 32 + q * 8];
      acc = __builtin_amdgcn_mfma_f32_16x16x32_bf16(a, bf, acc, 0, 0, 0);
    }
    int ncol = n0 + lr;
    if (ncol < Nn) {
#pragma unroll
      for (int reg = 0; reg < 4; ++reg) {
        int hh = q * 4 + reg;
        if (hh < Hh) logits[((size_t)b * Hh + hh) * Nn + ncol] = acc[reg];
      }
    }
  }
}

// ---------------- softmax over n, write transposed attnT[b][n][h] -------------
__global__ __launch_bounds__(64) void k_softmax(const float* __restrict__ logits,
                                                float* __restrict__ attnT) {
  int bh = blockIdx.x;
  int b = bh / Hh, h = bh % Hh;
  const float* row = logits + (size_t)bh * Nn;
  int t = threadIdx.x;
  float vals[10];
  float m = -1e30f;
#pragma unroll
  for (int i = 0; i < 10; ++i) {
    int n = i * 64 + t;
    vals[i] = (n < Nn) ? row[n] : -1e30f;
    m = fmaxf(m, vals[i]);
  }
#pragma unroll
  for (int off = 32; off; off >>= 1) m = fmaxf(m, __shfl_down(m, off));
  m = __shfl(m, 0);
  float s = 0.f;
#pragma unroll
  for (int i = 0; i < 10; ++i) { vals[i] = __expf(vals[i] - m); s += vals[i]; }
#pragma unroll
  for (int off = 32; off; off >>= 1) s += __shfl_down(s, off);
  float inv = 1.f / __shfl(s, 0);
#pragma unroll
  for (int i = 0; i < 10; ++i) {
    int n = i * 64 + t;
    if (n < Nn) attnT[((size_t)b * Nn + n) * Hh + h] = vals[i] * inv;
  }
}

// ---------------- zero y ------------------------------------------------------
__global__ __launch_bounds__(256) void k_zero(float* __restrict__ y) {
  ((float4*)y)[blockIdx.x * 256 + threadIdx.x] = make_float4(0.f, 0.f, 0.f, 0.f);
}

// ---------------- k_y: y[b,h,c] += sum_{n in seg} attn * x ----------------------
#define YSEG 8
__global__ __launch_bounds__(192) void k_y(const float* __restrict__ x,
                                           const float* __restrict__ attnT,
                                           float* __restrict__ y) {
  int b = blockIdx.x / YSEG, seg = blockIdx.x % YSEG;
  int n0 = seg * Nn / YSEG, n1 = (seg + 1) * Nn / YSEG;
  int c4 = threadIdx.x;
  float4 acc[Hh];
#pragma unroll
  for (int h = 0; h < Hh; ++h) acc[h] = make_float4(0.f, 0.f, 0.f, 0.f);
  const float4* x4 = (const float4*)(x + (size_t)b * Nn * Cc);
  const float* at = attnT + (size_t)b * Nn * Hh;
#pragma unroll 8
  for (int n = n0; n < n1; ++n) {
    float4 xv = x4[(size_t)n * 192 + c4];
#pragma unroll
    for (int h = 0; h < Hh; ++h) {
      float a = at[n * Hh + h];  // block-uniform -> s_load
      acc[h].x += a * xv.x; acc[h].y += a * xv.y;
      acc[h].z += a * xv.z; acc[h].w += a * xv.w;
    }
  }
  float* yb = y + (size_t)b * Hh * Cc;
#pragma unroll
  for (int h = 0; h < Hh; ++h) {
    float* p = yb + h * Cc + c4 * 4;
    atomicAdd(p + 0, acc[h].x); atomicAdd(p + 1, acc[h].y);
    atomicAdd(p + 2, acc[h].z); atomicAdd(p + 3, acc[h].w);
  }
}

// ---------------- k_cls: cls[b,j] = Wv[j,:] . y[b,h(j),:] + bv[j] -------------
__global__ __launch_bounds__(128) void k_cls(const float* __restrict__ y,
                                             const float* __restrict__ qkv_w,
                                             const float* __restrict__ qkv_b,
                                             float* __restrict__ cls) {
  int b = blockIdx.x / 6, chunk = blockIdx.x % 6;
  int j = chunk * 128 + threadIdx.x;
  __shared__ float ys[2 * Cc];
  for (int idx = threadIdx.x; idx < 2 * Cc; idx += 128)
    ys[idx] = y[(size_t)b * Hh * Cc + (size_t)chunk * 2 * Cc + idx];
  __syncthreads();
  const float4* wr = (const float4*)(qkv_w + (size_t)(2 * Cc + j) * Cc);
  const float4* yv = (const float4*)&ys[((threadIdx.x >> 6) & 1) * Cc];
  float acc = qkv_b[2 * Cc + j];
#pragma unroll 8
  for (int c4 = 0; c4 < Cc / 4; ++c4) {
    float4 w = wr[c4], yy = yv[c4];
    acc += w.x * yy.x + w.y * yy.y + w.z * yy.z + w.w * yy.w;
  }
  cls[b * Cc + j] = acc;
}

// ---------------- k_proj: out[b,0,j] = proj_w[j,:] . cls[b,:] + proj_b[j] -----
__global__ __launch_bounds__(128) void k_proj(const float* __restrict__ cls,
                                              const float* __restrict__ proj_w,
                                              const float* __restrict__ proj_b,
                                              float* __restrict__ out) {
  int b = blockIdx.x / 6, chunk = blockIdx.x % 6;
  int j = chunk * 128 + threadIdx.x;
  __shared__ float cs[Cc];
  for (int idx = threadIdx.x; idx < Cc; idx += 128)
    cs[idx] = cls[b * Cc + idx];
  __syncthreads();
  const float4* wr = (const float4*)(proj_w + (size_t)j * Cc);
  const float4* cv = (const float4*)cs;
  float acc = proj_b[j];
#pragma unroll 8
  for (int c4 = 0; c4 < Cc / 4; ++c4) {
    float4 w = wr[c4], cc = cv[c4];
    acc += w.x * cc.x + w.y * cc.y + w.z * cc.z + w.w * cc.w;
  }
  out[(size_t)b * Nn * Cc + j] = acc;
}

extern "C" void kernel_launch(void* const* d_in, const int* in_sizes, int n_in,
                              void* d_out, int out_size, void* d_ws, size_t ws_size,
                              hipStream_t stream) {
  const float* x      = (const float*)d_in[0];
  const float* qkv_w  = (const float*)d_in[1];
  const float* qkv_b  = (const float*)d_in[2];
  const float* proj_w = (const float*)d_in[3];
  const float* proj_b = (const float*)d_in[4];
  float* out = (float*)d_out;
  float* ws = (float*)d_ws;

  unsigned short* rb = (unsigned short*)ws;   // 786,432 bf16
  float* logits = ws + 393216;
  float* attnT  = ws + 836352;
  float* y      = ws + 1279488;
  float* cls    = ws + 1869312;

  k_zero<<<576, 256, 0, stream>>>(y);
  k_qr<<<96, 256, 0, stream>>>(x, qkv_w, qkv_b, rb);
  k_main<<<Bz * MNT, 256, 0, stream>>>(x, rb, out, logits);
  k_softmax<<<Bz * Hh, 64, 0, stream>>>(logits, attnT);
  k_y<<<Bz * YSEG, 192, 0, stream>>>(x, attnT, y);
  k_cls<<<Bz * 6, 128, 0, stream>>>(y, qkv_w, qkv_b, cls);
  k_proj<<<Bz * 6, 128, 0, stream>>>(cls, proj_w, proj_b, out);
}

// Round 4
// 354.238 us; speedup vs baseline: 1.1485x; 1.1485x over previous
//
#include <hip/hip_runtime.h>

#define Bz 64
#define Nn 577
#define Cc 768
#define Hh 12
#define Dd 64
#define SCALE 0.125f

typedef __attribute__((ext_vector_type(8))) short short8;
typedef __attribute__((ext_vector_type(4))) float float4v;

__device__ __forceinline__ unsigned short bf16rne(float f) {
  unsigned u = __float_as_uint(f);
  u += 0x7FFFu + ((u >> 16) & 1u);
  return (unsigned short)(u >> 16);
}

__device__ __forceinline__ short8 cvt8(float4 a, float4 b) {
  short8 v;
  v[0] = (short)bf16rne(a.x); v[1] = (short)bf16rne(a.y);
  v[2] = (short)bf16rne(a.z); v[3] = (short)bf16rne(a.w);
  v[4] = (short)bf16rne(b.x); v[5] = (short)bf16rne(b.y);
  v[6] = (short)bf16rne(b.z); v[7] = (short)bf16rne(b.w);
  return v;
}

// ws layout (float units), total 1,967,616 floats = 7.87 MB:
//   rb     @ 0        : 786,432 bf16 (393,216 float slots) [B][24 s][4 q][16 m=h][8 j]
//   qf     @ 393216   : [B][C] fp32
//   logits @ 442368   : [B][H][N] fp32
//   attnT  @ 885504   : [B][N][H] fp32
//   y      @ 1328640  : [B][H][C] fp32 (zeroed, atomic-accumulated)
//   cls    @ 1918464  : [B][C] fp32

// ============ k_gemm64: C(64 x 768) = A(64 x 768) @ W_rows^T + bias ===========
// MODE 0: q   = X0 @ Wq^T      (A row stride Nn*Cc;  W rows j;        out q)
// MODE 1: cls = Y_h @ Wv^T     (A = y[b][h=jt>>2];   W rows 2C+j;     out cls)
// MODE 2: out0 = cls @ projW^T (A row stride Cc;     W rows j;        out row0)
// 192 blocks = one 16x16 tile each; 4 waves split K in quarters; LDS reduce.
template <int MODE>
__global__ __launch_bounds__(256) void k_gemm64(const float* __restrict__ A,
                                                const float* __restrict__ W,
                                                const float* __restrict__ bias,
                                                float* __restrict__ out) {
  int tile = blockIdx.x;            // 0..191
  int jt = tile % 48, bt = tile / 48;
  int wave = threadIdx.x >> 6, lane = threadIdx.x & 63;
  int m = lane & 15, quad = lane >> 4;
  int brow = bt * 16 + m;
  int jrow = jt * 16 + m;
  size_t aoff;
  if (MODE == 0)      aoff = (size_t)brow * (Nn * Cc);
  else if (MODE == 1) aoff = (size_t)brow * (Hh * Cc) + (size_t)(jt >> 2) * Cc;
  else                aoff = (size_t)brow * Cc;
  size_t woff = (MODE == 1) ? (size_t)(2 * Cc + jrow) * Cc : (size_t)jrow * Cc;
  const float4* Ap = (const float4*)(A + aoff) + wave * 48 + quad * 2;
  const float4* Wp = (const float4*)(W + woff) + wave * 48 + quad * 2;
  float4v acc = {0.f, 0.f, 0.f, 0.f};
#pragma unroll
  for (int s = 0; s < 6; ++s) {
    float4 a0 = Ap[s * 8], a1 = Ap[s * 8 + 1];
    float4 w0 = Wp[s * 8], w1 = Wp[s * 8 + 1];
    acc = __builtin_amdgcn_mfma_f32_16x16x32_bf16(cvt8(a0, a1), cvt8(w0, w1),
                                                  acc, 0, 0, 0);
  }
  __shared__ float red[4][64][4];
#pragma unroll
  for (int reg = 0; reg < 4; ++reg) red[wave][lane][reg] = acc[reg];
  __syncthreads();
  if (wave == 0) {
#pragma unroll
    for (int reg = 0; reg < 4; ++reg) {
      float v = red[0][lane][reg] + red[1][lane][reg] +
                red[2][lane][reg] + red[3][lane][reg];
      int j = jt * 16 + m;
      int bb = bt * 16 + quad * 4 + reg;
      float bv = (MODE == 1) ? bias[2 * Cc + j] : bias[j];
      if (MODE == 2) out[(size_t)bb * (Nn * Cc) + j] = v + bv;
      else           out[(size_t)bb * Cc + j] = v + bv;
    }
  }
}

// ====== k_r: rb[b][s][q][h][j] = bf16(SCALE * sum_d q[b,h,d] * Wk[h,d,c]) =====
// grid 12 h x 8 b-groups = 96 blocks, 256 threads (round-3 phase 2, standalone)
__global__ __launch_bounds__(256) void k_r(const float* __restrict__ qf,
                                           const float* __restrict__ qkv_w,
                                           unsigned short* __restrict__ rb) {
  int h = blockIdx.x % Hh, bg = blockIdx.x / Hh;
  int t = threadIdx.x;
  __shared__ float qs2[Dd][8];
  for (int idx = t; idx < 512; idx += 256) {
    int bb = idx >> 6, d = idx & 63;
    qs2[d][bb] = qf[(size_t)(bg * 8 + bb) * Cc + h * Dd + d];
  }
  __syncthreads();
  float acc[8][3];
#pragma unroll
  for (int bb = 0; bb < 8; ++bb)
#pragma unroll
    for (int i = 0; i < 3; ++i) acc[bb][i] = 0.f;
  const float* wk = qkv_w + (size_t)(Cc + h * Dd) * Cc;
  for (int d = 0; d < Dd; ++d) {
    float w0 = wk[(size_t)d * Cc + t];
    float w1 = wk[(size_t)d * Cc + t + 256];
    float w2 = wk[(size_t)d * Cc + t + 512];
    float4 qa = *(const float4*)&qs2[d][0];
    float4 qb = *(const float4*)&qs2[d][4];
    float qv[8] = {qa.x, qa.y, qa.z, qa.w, qb.x, qb.y, qb.z, qb.w};
#pragma unroll
    for (int bb = 0; bb < 8; ++bb) {
      acc[bb][0] += qv[bb] * w0;
      acc[bb][1] += qv[bb] * w1;
      acc[bb][2] += qv[bb] * w2;
    }
  }
#pragma unroll
  for (int bb = 0; bb < 8; ++bb) {
    size_t base = (size_t)(bg * 8 + bb) * 12288 + h * 8;
#pragma unroll
    for (int i = 0; i < 3; ++i) {
      int c = t + i * 256;
      int s = c >> 5, qq = (c >> 3) & 3, j = c & 7;
      rb[base + s * 512 + qq * 128 + j] = bf16rne(acc[bb][i] * SCALE);
    }
  }
}

// ===== k_logits: MFMA straight from global (no LDS, no barriers) ==============
// grid 64 b x 10 tiles (64 rows, 4 waves x 16 rows), block 256.
__global__ __launch_bounds__(256) void k_logits(const float* __restrict__ x,
                                                const unsigned short* __restrict__ rb,
                                                float* __restrict__ logits) {
  int b = blockIdx.x / 10, tile = blockIdx.x % 10;
  int wave = threadIdx.x >> 6, lane = threadIdx.x & 63;
  int m = lane & 15, quad = lane >> 4;
  int n = tile * 64 + wave * 16 + m;
  int nc = n > 576 ? 576 : n;
  const short8* ag = (const short8*)(rb + (size_t)b * 12288);
  const float4* xg = (const float4*)(x + (size_t)b * Nn * Cc) +
                     (size_t)nc * 192 + quad * 2;
  float4v acc = {0.f, 0.f, 0.f, 0.f};
#pragma unroll 8
  for (int s = 0; s < 24; ++s) {
    short8 a = ag[s * 64 + quad * 16 + m];
    float4 f0 = xg[s * 8], f1 = xg[s * 8 + 1];
    acc = __builtin_amdgcn_mfma_f32_16x16x32_bf16(a, cvt8(f0, f1), acc, 0, 0, 0);
  }
  if (n < Nn) {
#pragma unroll
    for (int reg = 0; reg < 4; ++reg) {
      int hh = quad * 4 + reg;
      if (hh < Hh) logits[((size_t)b * Hh + hh) * Nn + n] = acc[reg];
    }
  }
}

// ---------------- softmax over n, write transposed attnT[b][n][h] -------------
__global__ __launch_bounds__(64) void k_softmax(const float* __restrict__ logits,
                                                float* __restrict__ attnT) {
  int bh = blockIdx.x;
  int b = bh / Hh, h = bh % Hh;
  const float* row = logits + (size_t)bh * Nn;
  int t = threadIdx.x;
  float vals[10];
  float m = -1e30f;
#pragma unroll
  for (int i = 0; i < 10; ++i) {
    int n = i * 64 + t;
    vals[i] = (n < Nn) ? row[n] : -1e30f;
    m = fmaxf(m, vals[i]);
  }
#pragma unroll
  for (int off = 32; off; off >>= 1) m = fmaxf(m, __shfl_down(m, off));
  m = __shfl(m, 0);
  float s = 0.f;
#pragma unroll
  for (int i = 0; i < 10; ++i) { vals[i] = __expf(vals[i] - m); s += vals[i]; }
#pragma unroll
  for (int off = 32; off; off >>= 1) s += __shfl_down(s, off);
  float inv = 1.f / __shfl(s, 0);
#pragma unroll
  for (int i = 0; i < 10; ++i) {
    int n = i * 64 + t;
    if (n < Nn) attnT[((size_t)b * Nn + n) * Hh + h] = vals[i] * inv;
  }
}

// ---------------- zero y ------------------------------------------------------
__global__ __launch_bounds__(256) void k_zero(float* __restrict__ y) {
  ((float4*)y)[blockIdx.x * 256 + threadIdx.x] = make_float4(0.f, 0.f, 0.f, 0.f);
}

// ---------------- k_y: y[b,h,c] += sum_{n in seg} attn * x --------------------
#define YSEG 8
__global__ __launch_bounds__(192) void k_y(const float* __restrict__ x,
                                           const float* __restrict__ attnT,
                                           float* __restrict__ y) {
  int b = blockIdx.x / YSEG, seg = blockIdx.x % YSEG;
  int n0 = seg * Nn / YSEG, n1 = (seg + 1) * Nn / YSEG;
  int c4 = threadIdx.x;
  float4 acc[Hh];
#pragma unroll
  for (int h = 0; h < Hh; ++h) acc[h] = make_float4(0.f, 0.f, 0.f, 0.f);
  const float4* x4 = (const float4*)(x + (size_t)b * Nn * Cc);
  const float* at = attnT + (size_t)b * Nn * Hh;
#pragma unroll 8
  for (int n = n0; n < n1; ++n) {
    float4 xv = x4[(size_t)n * 192 + c4];
#pragma unroll
    for (int h = 0; h < Hh; ++h) {
      float a = at[n * Hh + h];  // block-uniform -> s_load
      acc[h].x += a * xv.x; acc[h].y += a * xv.y;
      acc[h].z += a * xv.z; acc[h].w += a * xv.w;
    }
  }
  float* yb = y + (size_t)b * Hh * Cc;
#pragma unroll
  for (int h = 0; h < Hh; ++h) {
    float* p = yb + h * Cc + c4 * 4;
    atomicAdd(p + 0, acc[h].x); atomicAdd(p + 1, acc[h].y);
    atomicAdd(p + 2, acc[h].z); atomicAdd(p + 3, acc[h].w);
  }
}

// ---------------- k_copy: out[:,1:,:] = x[:,1:,:]  (pure stream) --------------
__global__ __launch_bounds__(256) void k_copy(const float* __restrict__ x,
                                              float* __restrict__ out) {
  int idx = blockIdx.x * 256 + threadIdx.x;   // 262144 threads
  const float4* xi = (const float4*)x;
  float4* oo = (float4*)out;
  for (int i = idx; i < 7077888; i += 262144) {   // 64 * 576 * 192
    int b = i / 110592;                            // 576*192
    int r = i - b * 110592;
    size_t off = (size_t)b * 110784 + 192 + r;     // skip row 0 (192 float4)
    oo[off] = xi[off];
  }
}

extern "C" void kernel_launch(void* const* d_in, const int* in_sizes, int n_in,
                              void* d_out, int out_size, void* d_ws, size_t ws_size,
                              hipStream_t stream) {
  const float* x      = (const float*)d_in[0];
  const float* qkv_w  = (const float*)d_in[1];
  const float* qkv_b  = (const float*)d_in[2];
  const float* proj_w = (const float*)d_in[3];
  const float* proj_b = (const float*)d_in[4];
  float* out = (float*)d_out;
  float* ws = (float*)d_ws;

  unsigned short* rb = (unsigned short*)ws;    // 786,432 bf16
  float* qf     = ws + 393216;
  float* logits = ws + 442368;
  float* attnT  = ws + 885504;
  float* y      = ws + 1328640;
  float* cls    = ws + 1918464;

  k_zero<<<576, 256, 0, stream>>>(y);
  k_gemm64<0><<<192, 256, 0, stream>>>(x, qkv_w, qkv_b, qf);
  k_r<<<96, 256, 0, stream>>>(qf, qkv_w, rb);
  k_logits<<<Bz * 10, 256, 0, stream>>>(x, rb, logits);
  k_softmax<<<Bz * Hh, 64, 0, stream>>>(logits, attnT);
  k_y<<<Bz * YSEG, 192, 0, stream>>>(x, attnT, y);
  k_gemm64<1><<<192, 256, 0, stream>>>(y, qkv_w, qkv_b, cls);
  k_gemm64<2><<<192, 256, 0, stream>>>(cls, proj_w, proj_b, out);
  k_copy<<<1024, 256, 0, stream>>>(x, out);
}